// Round 2
// baseline (687.110 us; speedup 1.0000x reference)
//
#include <hip/hip_runtime.h>

// VQ-VAE VectorQuantizer forward, MI355X (gfx950)
// inputs:  d_in[0] = inputs  [64,32,32,64] f32  (N=65536 rows, D=64)
//          d_in[1] = context [1] (unused)
//          d_in[2] = embeddings [64,512] f32    (D=64, K=512)
// out (flat f32, concatenated):
//   quantized [4194304] | loss [1] | perplexity [1] | encodings [33554432]
//   | encoding_indices [65536] (as float) | distances [33554432]

#define NROWS 65536
#define DIM 64
#define KCODES 512
#define TILE 16
#define NTILES 2
#define ROWS_PER_BLOCK 32

#define QUANT_OFF 0ull
#define LOSS_OFF  4194304ull
#define PERP_OFF  4194305ull
#define ENC_OFF   4194306ull
#define IDX_OFF   37748738ull
#define DIST_OFF  37814274ull

__global__ __launch_bounds__(512, 4) void vq_main(
    const float* __restrict__ inp, const float* __restrict__ emb,
    float* __restrict__ out, int* __restrict__ hist,
    float* __restrict__ loss_ws)
{
    __shared__ float s_dist[TILE][KCODES];      // 32 KB distance tile
    __shared__ float s_sumx2[ROWS_PER_BLOCK];
    __shared__ int   s_fi[TILE];
    __shared__ float s_loss[8];

    const int tid  = threadIdx.x;               // == codebook column k
    const int w    = tid >> 6;
    const int lane = tid & 63;
    const int rbase = blockIdx.x * ROWS_PER_BLOCK;

    // ---- codebook column tid -> VGPRs (coalesced per d); launch_bounds(512,4)
    // gives a ~128-VGPR budget so e[] actually stays resident (R0 had VGPR=56
    // => compiler was re-loading e per row)
    float e[DIM];
#pragma unroll
    for (int d = 0; d < DIM; ++d) e[d] = emb[d * KCODES + tid];

    float se0 = 0.f, se1 = 0.f, se2 = 0.f, se3 = 0.f;
#pragma unroll
    for (int d = 0; d < DIM; d += 4) {
        se0 = fmaf(e[d + 0], e[d + 0], se0);
        se1 = fmaf(e[d + 1], e[d + 1], se1);
        se2 = fmaf(e[d + 2], e[d + 2], se2);
        se3 = fmaf(e[d + 3], e[d + 3], se3);
    }
    const float sume2 = (se0 + se1) + (se2 + se3);

    // ---- per-row ||x||^2 for the block's 32 rows ----
    if (tid < ROWS_PER_BLOCK) {
        const float4* xr = (const float4*)(inp + (size_t)(rbase + tid) * DIM);
        float s0 = 0.f, s1 = 0.f, s2 = 0.f, s3 = 0.f;
#pragma unroll
        for (int j = 0; j < 16; ++j) {
            float4 v = xr[j];
            s0 = fmaf(v.x, v.x, s0); s1 = fmaf(v.y, v.y, s1);
            s2 = fmaf(v.z, v.z, s2); s3 = fmaf(v.w, v.w, s3);
        }
        s_sumx2[tid] = (s0 + s1) + (s2 + s3);
    }
    __syncthreads();

    float loss_acc = 0.f;

    for (int t = 0; t < NTILES; ++t) {
        const int rt = rbase + t * TILE;

        // ---- phase A: distances for 16 rows -> LDS (no shuffles, no barriers)
#pragma unroll 4
        for (int r0 = 0; r0 < TILE; ++r0) {
            const float4* xp4 = (const float4*)(inp + (size_t)(rt + r0) * DIM);
            float a0 = 0.f, a1 = 0.f, a2 = 0.f, a3 = 0.f;
#pragma unroll
            for (int j = 0; j < 16; ++j) {
                float4 xv = xp4[j];          // block-uniform -> scalar/broadcast
                a0 = fmaf(xv.x, e[4 * j + 0], a0);
                a1 = fmaf(xv.y, e[4 * j + 1], a1);
                a2 = fmaf(xv.z, e[4 * j + 2], a2);
                a3 = fmaf(xv.w, e[4 * j + 3], a3);
            }
            const float dot = (a0 + a1) + (a2 + a3);
            s_dist[r0][tid] = fmaf(-2.f, dot, s_sumx2[t * TILE + r0] + sume2);
        }
        __syncthreads();

        // ---- phase B: argmin, 32 threads per row (tie -> smallest k) ----
        {
            const int g  = tid >> 5;   // row 0..15
            const int t0 = tid & 31;
            float bd = 3.4e38f; int bk = KCODES;
#pragma unroll
            for (int j = 0; j < 16; ++j) {
                const int kk = j * 32 + t0;     // ascending -> strict < keeps first
                const float d = s_dist[g][kk];
                if (d < bd) { bd = d; bk = kk; }
            }
#pragma unroll
            for (int off = 16; off; off >>= 1) {   // stays within 32-group
                const float od = __shfl_xor(bd, off);
                const int   ok = __shfl_xor(bk, off);
                if (od < bd || (od == bd && ok < bk)) { bd = od; bk = ok; }
            }
            if (t0 == 0) {
                s_fi[g] = bk;
                loss_acc += bd;                     // sum_d(q-x)^2 == min dist
                (out + IDX_OFF)[rt + g] = (float)bk;
                atomicAdd(&hist[bk], 1);
            }
        }
        __syncthreads();

        // ---- phase C: float4 writebacks ----
        // distances: contiguous 16x512 tile copy, 4 float4 per thread
        float* dist_out = out + DIST_OFF + (size_t)rt * KCODES;
        const float4* sd4 = (const float4*)(&s_dist[0][0]);
#pragma unroll
        for (int i = 0; i < 4; ++i)
            ((float4*)dist_out)[i * 512 + tid] = sd4[i * 512 + tid];

        // encodings one-hot: same geometry, computed in-register
        float* enc_out = out + ENC_OFF + (size_t)rt * KCODES;
#pragma unroll
        for (int i = 0; i < 4; ++i) {
            const int idx = i * 512 + tid;
            const int row = idx >> 7;            // 128 float4 per row
            const int c0  = (idx & 127) << 2;
            const int fi  = s_fi[row];
            float4 v;
            v.x = (c0     == fi) ? 1.f : 0.f;
            v.y = (c0 + 1 == fi) ? 1.f : 0.f;
            v.z = (c0 + 2 == fi) ? 1.f : 0.f;
            v.w = (c0 + 3 == fi) ? 1.f : 0.f;
            ((float4*)enc_out)[idx] = v;
        }

        // quantized: 16 rows x 16 float4; gather from emb (L2-resident)
        if (tid < 256) {
            const int row = tid >> 4, c4 = tid & 15;
            const int fi = s_fi[row];
            const int d0 = c4 * 4;
            float4 q;
            q.x = emb[(d0 + 0) * KCODES + fi];
            q.y = emb[(d0 + 1) * KCODES + fi];
            q.z = emb[(d0 + 2) * KCODES + fi];
            q.w = emb[(d0 + 3) * KCODES + fi];
            ((float4*)(out + QUANT_OFF + (size_t)(rt + row) * DIM))[c4] = q;
        }
        __syncthreads();   // s_dist/s_fi reused next tile
    }

    // ---- loss: one atomic per block ----
#pragma unroll
    for (int off = 32; off; off >>= 1) loss_acc += __shfl_xor(loss_acc, off);
    if (lane == 0) s_loss[w] = loss_acc;
    __syncthreads();
    if (tid == 0) {
        float s = 0.f;
#pragma unroll
        for (int i = 0; i < 8; ++i) s += s_loss[i];
        atomicAdd(loss_ws, s);
    }
}

__global__ __launch_bounds__(512) void vq_final(
    const int* __restrict__ hist, const float* __restrict__ loss_ws,
    float* __restrict__ out)
{
    __shared__ float s_red[8];
    const int tid = threadIdx.x;
    const int w = tid >> 6, lane = tid & 63;

    float p = (float)hist[tid] * (1.f / 65536.f);
    float t = p * logf(p + 1e-10f);   // p==0 -> 0 * finite = 0
#pragma unroll
    for (int off = 32; off; off >>= 1) t += __shfl_xor(t, off);
    if (lane == 0) s_red[w] = t;
    __syncthreads();
    if (tid == 0) {
        float s = 0.f;
#pragma unroll
        for (int i = 0; i < 8; ++i) s += s_red[i];
        out[PERP_OFF] = expf(-s);
        // loss = (1 + 0.25) * mean((q - x)^2) over 64*32*32*64 elements
        out[LOSS_OFF] = loss_ws[0] * (1.25f / 4194304.f);
    }
}

extern "C" void kernel_launch(void* const* d_in, const int* in_sizes, int n_in,
                              void* d_out, int out_size, void* d_ws, size_t ws_size,
                              hipStream_t stream) {
    const float* inp = (const float*)d_in[0];
    const float* emb = (const float*)d_in[2];
    float* out = (float*)d_out;
    int*   hist    = (int*)d_ws;                       // 512 ints
    float* loss_ws = (float*)((char*)d_ws + 2048);     // 1 float

    hipMemsetAsync(d_ws, 0, 2052, stream);
    vq_main<<<dim3(NROWS / ROWS_PER_BLOCK), dim3(512), 0, stream>>>(
        inp, emb, out, hist, loss_ws);
    vq_final<<<dim3(1), dim3(512), 0, stream>>>(hist, loss_ws, out);
}

// Round 4
// 271.345 us; speedup vs baseline: 2.5322x; 2.5322x over previous
//
#include <hip/hip_runtime.h>

// VQ-VAE VectorQuantizer forward, MI355X (gfx950)
// inputs:  d_in[0] = inputs  [64,32,32,64] f32  (N=65536 rows, D=64)
//          d_in[1] = context [1] (unused)
//          d_in[2] = embeddings [64,512] f32    (D=64, K=512)
// out (flat f32): quantized[4194304] | loss[1] | perplexity[1] |
//   encodings[33554432] | encoding_indices[65536] | distances[33554432]

#define NROWS 65536
#define DIM 64
#define KCODES 512
#define ROWS_PER_BLOCK 256
#define CHUNK 32
#define NCHUNK 8

#define QUANT_OFF 0ull
#define LOSS_OFF  4194304ull
#define PERP_OFF  4194305ull
#define ENC_OFF   4194306ull
#define IDX_OFF   37748738ull
#define DIST_OFF  37814274ull

typedef float f32x4 __attribute__((ext_vector_type(4)));

__global__ __launch_bounds__(512, 2) void vq_main(
    const float* __restrict__ inp, const float* __restrict__ emb,
    float* __restrict__ out, int* __restrict__ hist,
    float* __restrict__ loss_ws)
{
    // E repacked: s_E4[dq*512 + k] = {E[4dq][k], E[4dq+1][k], E[4dq+2][k], E[4dq+3][k]}
    __shared__ float4 s_E4[16 * KCODES];          // 128 KB
    __shared__ float  s_sumx2[ROWS_PER_BLOCK];    // 1 KB
    __shared__ float  s_cd[2][8][CHUNK];          // 2 KB
    __shared__ int    s_ck[2][8][CHUNK];          // 2 KB
    __shared__ int    s_fi[2][CHUNK];             // 256 B

    const int tid  = threadIdx.x;                 // == this thread's k
    const int w    = tid >> 6;
    const int lane = tid & 63;
    const int rbase = blockIdx.x * ROWS_PER_BLOCK;

    // ---- stage E -> LDS (coalesced global f4 reads, scattered b32 LDS writes;
    //      once per block) ----
    {
        const float4* g4 = (const float4*)emb;    // [64][128] float4
#pragma unroll
        for (int i = 0; i < 16; ++i) {
            const int idx = i * 512 + tid;        // f4 index 0..8191
            const int d   = idx >> 7;             // 0..63
            const int k0  = (idx & 127) << 2;
            const float4 v = g4[idx];
            float* base = (float*)&s_E4[(d >> 2) * KCODES];
            const int sub = d & 3;
            base[(k0 + 0) * 4 + sub] = v.x;
            base[(k0 + 1) * 4 + sub] = v.y;
            base[(k0 + 2) * 4 + sub] = v.z;
            base[(k0 + 3) * 4 + sub] = v.w;
        }
    }

    // ---- per-row ||x||^2 (256 rows, one thread each) ----
    if (tid < ROWS_PER_BLOCK) {
        const float4* xr = (const float4*)(inp + (size_t)(rbase + tid) * DIM);
        float s0 = 0.f, s1 = 0.f, s2 = 0.f, s3 = 0.f;
#pragma unroll
        for (int j = 0; j < 16; ++j) {
            const float4 v = xr[j];
            s0 = fmaf(v.x, v.x, s0); s1 = fmaf(v.y, v.y, s1);
            s2 = fmaf(v.z, v.z, s2); s3 = fmaf(v.w, v.w, s3);
        }
        s_sumx2[tid] = (s0 + s1) + (s2 + s3);
    }
    __syncthreads();

    // ---- ||e_k||^2 for this thread's k (conflict-free b128 reads) ----
    float sume2 = 0.f;
#pragma unroll
    for (int dq = 0; dq < 16; ++dq) {
        const float4 ev = s_E4[dq * KCODES + tid];
        sume2 = fmaf(ev.x, ev.x, sume2);
        sume2 = fmaf(ev.y, ev.y, sume2);
        sume2 = fmaf(ev.z, ev.z, sume2);
        sume2 = fmaf(ev.w, ev.w, sume2);
    }

    float loss_acc = 0.f;

    for (int c = 0; c < NCHUNK; ++c) {
        const int par = c & 1;
        const int r0  = rbase + c * CHUNK;

        float acc[CHUNK];
#pragma unroll
        for (int r = 0; r < CHUNK; ++r) acc[r] = 0.f;

        // ---- dot products: 1 ds_read_b128 (E) per 4 d; x via scalar loads ----
        for (int dq = 0; dq < 16; ++dq) {
            const float4 e4 = s_E4[dq * KCODES + tid];
            const float4* xrow = (const float4*)(inp + (size_t)r0 * DIM) + dq;
#pragma unroll
            for (int r = 0; r < CHUNK; ++r) {
                const float4 xv = xrow[r * 16];   // block-uniform -> s_load_dwordx4
                acc[r] = fmaf(xv.x, e4.x, acc[r]);
                acc[r] = fmaf(xv.y, e4.y, acc[r]);
                acc[r] = fmaf(xv.z, e4.z, acc[r]);
                acc[r] = fmaf(xv.w, e4.w, acc[r]);
            }
        }

        // ---- to distances ----
#pragma unroll
        for (int r = 0; r < CHUNK; ++r)
            acc[r] = fmaf(-2.f, acc[r], s_sumx2[c * CHUNK + r] + sume2);

        // ---- wave argmin per row: min-only shuffles + ballot for the lane ----
#pragma unroll
        for (int r = 0; r < CHUNK; ++r) {
            float bd = acc[r];
#pragma unroll
            for (int off = 32; off; off >>= 1)
                bd = fminf(bd, __shfl_xor(bd, off));
            const unsigned long long m = __ballot(acc[r] == bd);
            if (lane == 0) {
                s_cd[par][w][r] = bd;
                s_ck[par][w][r] = (w << 6) + (int)__builtin_ctzll(m);
            }
        }
        __syncthreads();

        // ---- cross-wave combine (tie -> smallest k via ascending order) ----
        if (tid < CHUNK) {
            float fd = s_cd[par][0][tid];
            int   fi = s_ck[par][0][tid];
#pragma unroll
            for (int ww = 1; ww < 8; ++ww) {
                const float od = s_cd[par][ww][tid];
                const int   ok = s_ck[par][ww][tid];
                if (od < fd || (od == fd && ok < fi)) { fd = od; fi = ok; }
            }
            s_fi[par][tid] = fi;
            loss_acc += fd;                       // sum_d(q-x)^2 == min dist
            (out + IDX_OFF)[r0 + tid] = (float)fi;
            atomicAdd(&hist[fi], 1);
        }
        __syncthreads();

        // ---- distances: coalesced b32 streaming stores ----
        {
            float* dptr = out + DIST_OFF + (size_t)r0 * KCODES + tid;
#pragma unroll
            for (int r = 0; r < CHUNK; ++r)
                __builtin_nontemporal_store(acc[r], dptr + r * KCODES);
        }

        // ---- encodings one-hot: f32x4 streaming stores ----
        {
            f32x4* eptr = (f32x4*)(out + ENC_OFF + (size_t)r0 * KCODES);
#pragma unroll
            for (int i = 0; i < 8; ++i) {
                const int idx = i * 512 + tid;
                const int rr  = idx >> 7;
                const int c0  = (idx & 127) << 2;
                const int fi  = s_fi[par][rr];
                f32x4 v;
                v.x = (c0     == fi) ? 1.f : 0.f;
                v.y = (c0 + 1 == fi) ? 1.f : 0.f;
                v.z = (c0 + 2 == fi) ? 1.f : 0.f;
                v.w = (c0 + 3 == fi) ? 1.f : 0.f;
                __builtin_nontemporal_store(v, eptr + idx);
            }
        }

        // ---- quantized: one b128 LDS gather + float4 store per thread ----
        {
            const int rr = tid >> 4, c4 = tid & 15;
            const int fi = s_fi[par][rr];
            const float4 q = s_E4[c4 * KCODES + fi];
            ((float4*)(out + QUANT_OFF + (size_t)(r0 + rr) * DIM))[c4] = q;
        }
    }

    // ---- loss: one atomic per block (only lanes 0..31 of wave 0 are nonzero) ----
    if (w == 0) {
#pragma unroll
        for (int off = 32; off; off >>= 1) loss_acc += __shfl_xor(loss_acc, off);
        if (lane == 0) atomicAdd(loss_ws, loss_acc);
    }
}

__global__ __launch_bounds__(512) void vq_final(
    const int* __restrict__ hist, const float* __restrict__ loss_ws,
    float* __restrict__ out)
{
    __shared__ float s_red[8];
    const int tid = threadIdx.x;
    const int w = tid >> 6, lane = tid & 63;

    float p = (float)hist[tid] * (1.f / 65536.f);
    float t = p * logf(p + 1e-10f);   // p==0 -> 0
#pragma unroll
    for (int off = 32; off; off >>= 1) t += __shfl_xor(t, off);
    if (lane == 0) s_red[w] = t;
    __syncthreads();
    if (tid == 0) {
        float s = 0.f;
#pragma unroll
        for (int i = 0; i < 8; ++i) s += s_red[i];
        out[PERP_OFF] = expf(-s);
        // loss = (1 + 0.25) * mean((q - x)^2) over 4194304 elements
        out[LOSS_OFF] = loss_ws[0] * (1.25f / 4194304.f);
    }
}

extern "C" void kernel_launch(void* const* d_in, const int* in_sizes, int n_in,
                              void* d_out, int out_size, void* d_ws, size_t ws_size,
                              hipStream_t stream) {
    const float* inp = (const float*)d_in[0];
    const float* emb = (const float*)d_in[2];
    float* out = (float*)d_out;
    int*   hist    = (int*)d_ws;                       // 512 ints
    float* loss_ws = (float*)((char*)d_ws + 2048);     // 1 float

    (void)hipMemsetAsync(d_ws, 0, 2052, stream);
    vq_main<<<dim3(NROWS / ROWS_PER_BLOCK), dim3(512), 0, stream>>>(
        inp, emb, out, hist, loss_ws);
    vq_final<<<dim3(1), dim3(512), 0, stream>>>(hist, loss_ws, out);
}

// Round 5
// 140.770 us; speedup vs baseline: 4.8811x; 1.9276x over previous
//
#include <hip/hip_runtime.h>

// VQ-VAE VectorQuantizer forward, MI355X (gfx950)
// inputs:  d_in[0] = inputs  [64,32,32,64] f32  (N=65536 rows, D=64)
//          d_in[1] = context [1] (unused)
//          d_in[2] = embeddings [64,512] f32    (D=64, K=512)
// out (flat f32): quantized[4194304] | loss[1] | perplexity[1] |
//   encodings[33554432] | encoding_indices[65536] | distances[33554432]

#define NROWS 65536
#define DIM 64
#define KCODES 512
#define ROWS_PER_BLOCK 256
#define CHUNK_ROWS 64
#define NCHUNK 4
#define RPT 8   // rows per wave per chunk
#define GPT 8   // k-groups (of 64) per lane

#define QUANT_OFF 0ull
#define LOSS_OFF  4194304ull
#define PERP_OFF  4194305ull
#define ENC_OFF   4194306ull
#define IDX_OFF   37748738ull
#define DIST_OFF  37814274ull

typedef float f32x4 __attribute__((ext_vector_type(4)));

__global__ __launch_bounds__(512, 2) void vq_main(
    const float* __restrict__ inp, const float* __restrict__ emb,
    float* __restrict__ out, int* __restrict__ hist,
    float* __restrict__ loss_ws)
{
    // s_E4[dq*512 + k] = {E[4dq][k], E[4dq+1][k], E[4dq+2][k], E[4dq+3][k]}
    __shared__ f32x4 s_E4[16 * KCODES];           // 128 KB
    __shared__ f32x4 s_X[CHUNK_ROWS * 16];        // 16 KB  [row][dq]
    __shared__ float s_sumx2[ROWS_PER_BLOCK];     // 1 KB

    const int tid  = threadIdx.x;
    const int w    = tid >> 6;
    const int lane = tid & 63;
    const int rbase = blockIdx.x * ROWS_PER_BLOCK;

    // ---- stage E -> LDS repacked; lanes spread over 4 d-rows so the b32
    //      scatter writes hit 8 distinct banks (8-way, was 32-way) ----
    {
        const f32x4* g4 = (const f32x4*)emb;      // [64][128]
        const int sub = tid & 3;
        const int c   = tid >> 2;                 // f4-col 0..127
#pragma unroll
        for (int i = 0; i < 16; ++i) {
            const int d = i * 4 + sub;
            const f32x4 v = g4[d * 128 + c];
            float* base = (float*)&s_E4[(d >> 2) * KCODES + c * 4];
            base[0 * 4 + sub] = v.x;
            base[1 * 4 + sub] = v.y;
            base[2 * 4 + sub] = v.z;
            base[3 * 4 + sub] = v.w;
        }
    }

    // ---- per-row ||x||^2 (256 rows; global reads, L2-hot) ----
    if (tid < ROWS_PER_BLOCK) {
        const f32x4* xr = (const f32x4*)(inp + (size_t)(rbase + tid) * DIM);
        float s0 = 0.f, s1 = 0.f, s2 = 0.f, s3 = 0.f;
#pragma unroll
        for (int j = 0; j < 16; ++j) {
            const f32x4 v = xr[j];
            s0 = fmaf(v.x, v.x, s0); s1 = fmaf(v.y, v.y, s1);
            s2 = fmaf(v.z, v.z, s2); s3 = fmaf(v.w, v.w, s3);
        }
        s_sumx2[tid] = (s0 + s1) + (s2 + s3);
    }

    // ---- preload X chunk 0 into regs (coalesced) ----
    f32x4 xa = ((const f32x4*)(inp + (size_t)rbase * DIM))[tid];
    f32x4 xb = ((const f32x4*)(inp + (size_t)rbase * DIM))[512 + tid];

    __syncthreads();

    // ---- ||e_k||^2 for this lane's 8 k's (conflict-free b128 reads) ----
    float sume2[GPT];
#pragma unroll
    for (int g = 0; g < GPT; ++g) sume2[g] = 0.f;
#pragma unroll 2
    for (int dq = 0; dq < 16; ++dq) {
#pragma unroll
        for (int g = 0; g < GPT; ++g) {
            const f32x4 ev = s_E4[dq * KCODES + g * 64 + lane];
            sume2[g] = fmaf(ev.x, ev.x, sume2[g]);
            sume2[g] = fmaf(ev.y, ev.y, sume2[g]);
            sume2[g] = fmaf(ev.z, ev.z, sume2[g]);
            sume2[g] = fmaf(ev.w, ev.w, sume2[g]);
        }
    }

    float loss_acc = 0.f;
    const int rl0 = w * RPT;                      // this wave's local row base

#pragma unroll 1
    for (int c = 0; c < NCHUNK; ++c) {
        // publish the prefetched chunk to LDS (linear b128, conflict-free)
        ((f32x4*)s_X)[tid]       = xa;
        ((f32x4*)s_X)[512 + tid] = xb;
        __syncthreads();

        // ---- 8x8 register tile: lane k = g*64+lane, wave rows rl0..rl0+7.
        //      Pure-DS operands: e per-lane b128, x uniform-addr broadcast. ----
        float acc[RPT][GPT];
#pragma unroll
        for (int r = 0; r < RPT; ++r)
#pragma unroll
            for (int g = 0; g < GPT; ++g) acc[r][g] = 0.f;

#pragma unroll 2
        for (int dq = 0; dq < 16; ++dq) {
            f32x4 e4[GPT];
#pragma unroll
            for (int g = 0; g < GPT; ++g)
                e4[g] = s_E4[dq * KCODES + g * 64 + lane];
#pragma unroll
            for (int r = 0; r < RPT; ++r) {
                const f32x4 xv = s_X[(rl0 + r) * 16 + dq];   // broadcast
#pragma unroll
                for (int g = 0; g < GPT; ++g) {
                    acc[r][g] = fmaf(xv.x, e4[g].x, acc[r][g]);
                    acc[r][g] = fmaf(xv.y, e4[g].y, acc[r][g]);
                    acc[r][g] = fmaf(xv.z, e4[g].z, acc[r][g]);
                    acc[r][g] = fmaf(xv.w, e4[g].w, acc[r][g]);
                }
            }
        }
        __syncthreads();                          // all waves done with s_X

        // prefetch next chunk now; HBM latency hides under the epilogue
        f32x4 xna, xnb;
        if (c + 1 < NCHUNK) {
            const f32x4* nx =
                (const f32x4*)(inp + (size_t)(rbase + (c + 1) * CHUNK_ROWS) * DIM);
            xna = nx[tid];
            xnb = nx[512 + tid];
        }

        // ---- epilogue: per-row distances, wave-local argmin, stores ----
#pragma unroll
        for (int r = 0; r < RPT; ++r) {
            const float sx2 = s_sumx2[c * CHUNK_ROWS + rl0 + r];
            float dd[GPT];
#pragma unroll
            for (int g = 0; g < GPT; ++g)
                dd[g] = fmaf(-2.f, acc[r][g], sx2 + sume2[g]);

            // wave min
            float bd = dd[0];
#pragma unroll
            for (int g = 1; g < GPT; ++g) bd = fminf(bd, dd[g]);
#pragma unroll
            for (int off = 32; off; off >>= 1)
                bd = fminf(bd, __shfl_xor(bd, off));
            // smallest k achieving bd (descending g -> smallest matching g)
            int ck = 0x7fffffff;
#pragma unroll
            for (int g = GPT - 1; g >= 0; --g)
                if (dd[g] == bd) ck = g * 64 + lane;
#pragma unroll
            for (int off = 32; off; off >>= 1) {
                const int ok = __shfl_xor(ck, off);
                ck = ok < ck ? ok : ck;
            }

            const int row = rbase + c * CHUNK_ROWS + rl0 + r;

            float* dp = out + DIST_OFF + (size_t)row * KCODES + lane;
#pragma unroll
            for (int g = 0; g < GPT; ++g)
                __builtin_nontemporal_store(dd[g], dp + g * 64);

            float* ep = out + ENC_OFF + (size_t)row * KCODES + lane;
#pragma unroll
            for (int g = 0; g < GPT; ++g)
                __builtin_nontemporal_store((g * 64 + lane) == ck ? 1.f : 0.f,
                                            ep + g * 64);

            // quantized row: gather E[lane][ck] from global (L2-hot), coalesced store
            const float q = emb[lane * KCODES + ck];
            out[QUANT_OFF + (size_t)row * DIM + lane] = q;

            if (lane == 0) {
                out[IDX_OFF + row] = (float)ck;
                atomicAdd(&hist[ck], 1);
                loss_acc += bd;                   // sum_d(q-x)^2 == min dist
            }
        }

        if (c + 1 < NCHUNK) { xa = xna; xb = xnb; }
    }

    if (lane == 0) atomicAdd(loss_ws, loss_acc);  // 8 atomics/block
}

__global__ __launch_bounds__(512) void vq_final(
    const int* __restrict__ hist, const float* __restrict__ loss_ws,
    float* __restrict__ out)
{
    __shared__ float s_red[8];
    const int tid = threadIdx.x;
    const int w = tid >> 6, lane = tid & 63;

    float p = (float)hist[tid] * (1.f / 65536.f);
    float t = p * logf(p + 1e-10f);   // p==0 -> 0
#pragma unroll
    for (int off = 32; off; off >>= 1) t += __shfl_xor(t, off);
    if (lane == 0) s_red[w] = t;
    __syncthreads();
    if (tid == 0) {
        float s = 0.f;
#pragma unroll
        for (int i = 0; i < 8; ++i) s += s_red[i];
        out[PERP_OFF] = expf(-s);
        // loss = (1 + 0.25) * mean((q - x)^2) over 4194304 elements
        out[LOSS_OFF] = loss_ws[0] * (1.25f / 4194304.f);
    }
}

extern "C" void kernel_launch(void* const* d_in, const int* in_sizes, int n_in,
                              void* d_out, int out_size, void* d_ws, size_t ws_size,
                              hipStream_t stream) {
    const float* inp = (const float*)d_in[0];
    const float* emb = (const float*)d_in[2];
    float* out = (float*)d_out;
    int*   hist    = (int*)d_ws;                       // 512 ints
    float* loss_ws = (float*)((char*)d_ws + 2048);     // 1 float

    (void)hipMemsetAsync(d_ws, 0, 2052, stream);
    vq_main<<<dim3(NROWS / ROWS_PER_BLOCK), dim3(512), 0, stream>>>(
        inp, emb, out, hist, loss_ws);
    vq_final<<<dim3(1), dim3(512), 0, stream>>>(hist, loss_ws, out);
}

// Round 6
// 135.626 us; speedup vs baseline: 5.0662x; 1.0379x over previous
//
#include <hip/hip_runtime.h>

// VQ-VAE VectorQuantizer forward, MI355X (gfx950)
// inputs:  d_in[0] = inputs  [64,32,32,64] f32  (N=65536 rows, D=64)
//          d_in[1] = context [1] (unused)
//          d_in[2] = embeddings [64,512] f32    (D=64, K=512)
// out (flat f32): quantized[4194304] | loss[1] | perplexity[1] |
//   encodings[33554432] | encoding_indices[65536] | distances[33554432]

#define NROWS 65536
#define DIM 64
#define KCODES 512
#define ROWS_PER_BLOCK 128
#define CHUNK_ROWS 64
#define NCHUNK 2
#define RPT 8   // rows per wave per chunk

#define QUANT_OFF 0ull
#define LOSS_OFF  4194304ull
#define PERP_OFF  4194305ull
#define ENC_OFF   4194306ull
#define IDX_OFF   37748738ull
#define DIST_OFF  37814274ull

typedef float f32x4 __attribute__((ext_vector_type(4)));

__global__ __launch_bounds__(512, 4) void vq_main(
    const float* __restrict__ inp, const float* __restrict__ emb,
    float* __restrict__ out, int* __restrict__ hist,
    float* __restrict__ loss_ws)
{
    __shared__ f32x4 s_X[CHUNK_ROWS * 16];        // 16 KB  [row][dq]
    __shared__ float s_sumx2[ROWS_PER_BLOCK];     // 512 B

    const int tid  = threadIdx.x;
    const int w    = tid >> 6;
    const int lane = tid & 63;
    const int rbase = blockIdx.x * ROWS_PER_BLOCK;
    const int rl0  = w * RPT;                     // wave's local row base
    // lane owns k = h*256 + lane*4 + j  (h=0,1; j=0..3) -> f4-index h*64+lane

    // ---- per-row ||x||^2 ----
    if (tid < ROWS_PER_BLOCK) {
        const f32x4* xr = (const f32x4*)(inp + (size_t)(rbase + tid) * DIM);
        float s0 = 0.f, s1 = 0.f, s2 = 0.f, s3 = 0.f;
#pragma unroll
        for (int j = 0; j < 16; ++j) {
            const f32x4 v = xr[j];
            s0 = fmaf(v.x, v.x, s0); s1 = fmaf(v.y, v.y, s1);
            s2 = fmaf(v.z, v.z, s2); s3 = fmaf(v.w, v.w, s3);
        }
        s_sumx2[tid] = (s0 + s1) + (s2 + s3);
    }

    // ---- prefetch x chunk 0 (coalesced; 1024 f4 / 512 thr) ----
    f32x4 xa = ((const f32x4*)(inp + (size_t)rbase * DIM))[tid];
    f32x4 xb = ((const f32x4*)(inp + (size_t)rbase * DIM))[512 + tid];

    f32x4 sume2_0 = {0.f, 0.f, 0.f, 0.f};
    f32x4 sume2_1 = {0.f, 0.f, 0.f, 0.f};
    float loss_acc = 0.f;

    const float* ebase = emb + lane * 4;          // + (dq*4+sub)*512 + h*256

#pragma unroll 1
    for (int c = 0; c < NCHUNK; ++c) {
        ((f32x4*)s_X)[tid]       = xa;
        ((f32x4*)s_X)[512 + tid] = xb;
        __syncthreads();

        f32x4 acc[RPT][2];
#pragma unroll
        for (int r = 0; r < RPT; ++r) {
            acc[r][0] = (f32x4){0.f, 0.f, 0.f, 0.f};
            acc[r][1] = (f32x4){0.f, 0.f, 0.f, 0.f};
        }

#pragma unroll 1
        for (int dq = 0; dq < 16; ++dq) {
            // E fragments from global (L2-hot): coalesced f32x4, 4 consecutive k
            f32x4 e0[4], e1[4];
#pragma unroll
            for (int sub = 0; sub < 4; ++sub) {
                e0[sub] = *(const f32x4*)(ebase + (dq * 4 + sub) * KCODES);
                e1[sub] = *(const f32x4*)(ebase + (dq * 4 + sub) * KCODES + 256);
            }
            if (c == 0) {                          // fold ||e||^2 into chunk 0
#pragma unroll
                for (int sub = 0; sub < 4; ++sub) {
                    sume2_0 = sume2_0 + e0[sub] * e0[sub];
                    sume2_1 = sume2_1 + e1[sub] * e1[sub];
                }
            }
#pragma unroll
            for (int r = 0; r < RPT; ++r) {
                const f32x4 xv = s_X[(rl0 + r) * 16 + dq];   // DS broadcast
                acc[r][0] = acc[r][0] + xv.x * e0[0];
                acc[r][1] = acc[r][1] + xv.x * e1[0];
                acc[r][0] = acc[r][0] + xv.y * e0[1];
                acc[r][1] = acc[r][1] + xv.y * e1[1];
                acc[r][0] = acc[r][0] + xv.z * e0[2];
                acc[r][1] = acc[r][1] + xv.z * e1[2];
                acc[r][0] = acc[r][0] + xv.w * e0[3];
                acc[r][1] = acc[r][1] + xv.w * e1[3];
            }
        }
        __syncthreads();                          // s_X free for next chunk

        // prefetch next x chunk; latency hides under the epilogue
        if (c + 1 < NCHUNK) {
            const f32x4* nx =
                (const f32x4*)(inp + (size_t)(rbase + (c + 1) * CHUNK_ROWS) * DIM);
            xa = nx[tid];
            xb = nx[512 + tid];
        }

        // ---- epilogue: distances, wave argmin, vectorized stores ----
#pragma unroll
        for (int r = 0; r < RPT; ++r) {
            const int row = rbase + c * CHUNK_ROWS + rl0 + r;
            const float sx2 = s_sumx2[c * CHUNK_ROWS + rl0 + r];

            const f32x4 dd0 = (sume2_0 + sx2) + (-2.f) * acc[r][0];
            const f32x4 dd1 = (sume2_1 + sx2) + (-2.f) * acc[r][1];

            // wave min
            float bd = fminf(fminf(fminf(dd0.x, dd0.y), fminf(dd0.z, dd0.w)),
                             fminf(fminf(dd1.x, dd1.y), fminf(dd1.z, dd1.w)));
#pragma unroll
            for (int off = 32; off; off >>= 1)
                bd = fminf(bd, __shfl_xor(bd, off));

            // smallest k achieving bd: overwrite from largest k downward
            const int kb = lane * 4;
            int ck = 0x7fffffff;
            if (dd1.w == bd) ck = 256 + kb + 3;
            if (dd1.z == bd) ck = 256 + kb + 2;
            if (dd1.y == bd) ck = 256 + kb + 1;
            if (dd1.x == bd) ck = 256 + kb + 0;
            if (dd0.w == bd) ck = kb + 3;
            if (dd0.z == bd) ck = kb + 2;
            if (dd0.y == bd) ck = kb + 1;
            if (dd0.x == bd) ck = kb + 0;
#pragma unroll
            for (int off = 32; off; off >>= 1) {
                const int ok = __shfl_xor(ck, off);
                ck = ok < ck ? ok : ck;
            }

            // distances: 2 contiguous f32x4 NT stores (1 KB/instr)
            f32x4* dp = (f32x4*)(out + DIST_OFF) + (size_t)row * 128;
            __builtin_nontemporal_store(dd0, dp + lane);
            __builtin_nontemporal_store(dd1, dp + 64 + lane);

            // encodings one-hot: 2 contiguous f32x4 NT stores
            f32x4* ep = (f32x4*)(out + ENC_OFF) + (size_t)row * 128;
            const int cq = ck >> 2;
            f32x4 v0 = {0.f, 0.f, 0.f, 0.f};
            f32x4 v1 = {0.f, 0.f, 0.f, 0.f};
            if (cq == lane) {
                v0.x = (ck & 3) == 0 ? 1.f : 0.f;
                v0.y = (ck & 3) == 1 ? 1.f : 0.f;
                v0.z = (ck & 3) == 2 ? 1.f : 0.f;
                v0.w = (ck & 3) == 3 ? 1.f : 0.f;
            }
            if (cq == 64 + lane) {
                v1.x = (ck & 3) == 0 ? 1.f : 0.f;
                v1.y = (ck & 3) == 1 ? 1.f : 0.f;
                v1.z = (ck & 3) == 2 ? 1.f : 0.f;
                v1.w = (ck & 3) == 3 ? 1.f : 0.f;
            }
            __builtin_nontemporal_store(v0, ep + lane);
            __builtin_nontemporal_store(v1, ep + 64 + lane);

            // quantized row: gather E[lane][ck] (L2-hot), coalesced store
            const float q = emb[lane * KCODES + ck];
            out[QUANT_OFF + (size_t)row * DIM + lane] = q;

            if (lane == 0) {
                out[IDX_OFF + row] = (float)ck;
                atomicAdd(&hist[ck], 1);
                loss_acc += bd;                   // sum_d(q-x)^2 == min dist
            }
        }
    }

    if (lane == 0) atomicAdd(loss_ws, loss_acc);
}

__global__ __launch_bounds__(512) void vq_final(
    const int* __restrict__ hist, const float* __restrict__ loss_ws,
    float* __restrict__ out)
{
    __shared__ float s_red[8];
    const int tid = threadIdx.x;
    const int w = tid >> 6, lane = tid & 63;

    float p = (float)hist[tid] * (1.f / 65536.f);
    float t = p * logf(p + 1e-10f);   // p==0 -> 0
#pragma unroll
    for (int off = 32; off; off >>= 1) t += __shfl_xor(t, off);
    if (lane == 0) s_red[w] = t;
    __syncthreads();
    if (tid == 0) {
        float s = 0.f;
#pragma unroll
        for (int i = 0; i < 8; ++i) s += s_red[i];
        out[PERP_OFF] = expf(-s);
        // loss = (1 + 0.25) * mean((q - x)^2) over 4194304 elements
        out[LOSS_OFF] = loss_ws[0] * (1.25f / 4194304.f);
    }
}

extern "C" void kernel_launch(void* const* d_in, const int* in_sizes, int n_in,
                              void* d_out, int out_size, void* d_ws, size_t ws_size,
                              hipStream_t stream) {
    const float* inp = (const float*)d_in[0];
    const float* emb = (const float*)d_in[2];
    float* out = (float*)d_out;
    int*   hist    = (int*)d_ws;                       // 512 ints
    float* loss_ws = (float*)((char*)d_ws + 2048);     // 1 float

    (void)hipMemsetAsync(d_ws, 0, 2052, stream);
    vq_main<<<dim3(NROWS / ROWS_PER_BLOCK), dim3(512), 0, stream>>>(
        inp, emb, out, hist, loss_ws);
    vq_final<<<dim3(1), dim3(512), 0, stream>>>(hist, loss_ws, out);
}